// Round 1
// baseline (1427.063 us; speedup 1.0000x reference)
//
#include <hip/hip_runtime.h>
#include <math.h>

// MAGNN metapath attention aggregation, fused single-pass.
//   h:  [E, H=8, D=32] fp32 (read once, 1.024 GB -> HBM-bound)
//   er = sum_d h*attn_r; e = leaky_relu(er, 0.01)
//   edge-softmax grouped by sorted dst (online/flash-style), weighted sum, ELU.
// One wave per dst node: lane i owns float4 chunk i of the 256-float row
// (lanes 0..7 = head 0, etc). Edge row load = 64 lanes x 16 B = 1 KB coalesced.

constexpr int H = 8;
constexpr int D = 32;
constexpr int HD = H * D;          // 256 floats per row = 64 float4
constexpr float NEG_SLOPE = 0.01f;

__global__ __launch_bounds__(256) void magnn_fused(
    const float* __restrict__ h_meta,   // [E, 256]
    const float* __restrict__ attn_r,   // [256]
    const int*   __restrict__ dst,      // [E], sorted ascending
    float*       __restrict__ out,      // [N, 256]
    int E, int N)
{
    const int node = blockIdx.x * (blockDim.x >> 6) + (threadIdx.x >> 6);
    const int lane = threadIdx.x & 63;
    if (node >= N) return;

    // Wave-uniform binary search: edge range [start, end) for this node.
    int lo = 0, hi = E;
    while (lo < hi) {
        int mid = (lo + hi) >> 1;
        if (dst[mid] < node) lo = mid + 1; else hi = mid;
    }
    const int start = lo;
    hi = E;
    while (lo < hi) {
        int mid = (lo + hi) >> 1;
        if (dst[mid] <= node) lo = mid + 1; else hi = mid;
    }
    const int end = lo;

    // This lane's 4 attn_r coefficients (attn_r broadcast from L2 after first wave).
    const float4 ar = reinterpret_cast<const float4*>(attn_r)[lane];

    // Online softmax state. acc holds un-normalized weighted feature sum.
    float  m = -INFINITY;
    float  l = 0.0f;
    float4 acc = make_float4(0.0f, 0.0f, 0.0f, 0.0f);

    const float4* __restrict__ hrow = reinterpret_cast<const float4*>(h_meta);

    for (int e = start; e < end; ++e) {
        const float4 hv = hrow[e * 64 + lane];           // coalesced 1 KB / wave
        // partial dot for this lane's 4 elements
        float part = hv.x * ar.x + hv.y * ar.y + hv.z * ar.z + hv.w * ar.w;
        // reduce across the 8 lanes of this head (xor 1,2,4 stays in-group)
        part += __shfl_xor(part, 1);
        part += __shfl_xor(part, 2);
        part += __shfl_xor(part, 4);
        // leaky_relu
        const float el = part > 0.0f ? part : NEG_SLOPE * part;
        // online softmax update
        const float mn = fmaxf(m, el);
        const float sc = __expf(m - mn);    // exp(-inf)=0 on first edge
        const float p  = __expf(el - mn);
        l = l * sc + p;
        acc.x = acc.x * sc + p * hv.x;
        acc.y = acc.y * sc + p * hv.y;
        acc.z = acc.z * sc + p * hv.z;
        acc.w = acc.w * sc + p * hv.w;
        m = mn;
    }

    // normalize (degree-0 node: l==0 -> output elu(0)=0)
    const float inv = (l > 0.0f) ? 1.0f / l : 0.0f;
    float4 o;
    o.x = acc.x * inv;
    o.y = acc.y * inv;
    o.z = acc.z * inv;
    o.w = acc.w * inv;
    // elu (alpha=1)
    o.x = o.x > 0.0f ? o.x : expm1f(o.x);
    o.y = o.y > 0.0f ? o.y : expm1f(o.y);
    o.z = o.z > 0.0f ? o.z : expm1f(o.z);
    o.w = o.w > 0.0f ? o.w : expm1f(o.w);

    reinterpret_cast<float4*>(out)[node * 64 + lane] = o;
}

extern "C" void kernel_launch(void* const* d_in, const int* in_sizes, int n_in,
                              void* d_out, int out_size, void* d_ws, size_t ws_size,
                              hipStream_t stream) {
    const float* h_meta = (const float*)d_in[0];
    const float* attn_r = (const float*)d_in[1];
    const int*   dst    = (const int*)d_in[2];
    float*       out    = (float*)d_out;

    const int E = in_sizes[2];          // 1,000,000
    const int N = out_size / HD;        // 100,000

    const int waves_per_block = 4;      // 256 threads
    const int grid = (N + waves_per_block - 1) / waves_per_block;
    magnn_fused<<<grid, 256, 0, stream>>>(h_meta, attn_r, dst, out, E, N);
}

// Round 2
// 1308.142 us; speedup vs baseline: 1.0909x; 1.0909x over previous
//
#include <hip/hip_runtime.h>
#include <math.h>

// MAGNN metapath attention aggregation, fused single-pass.
//   h: [E, H=8, D=32] fp32 (1.024 GB, read exactly once -> HBM-bound, floor ~170us)
//   er = sum_d h*attn_r; e = leaky_relu(er); edge-softmax grouped by sorted dst
//   (online/flash-style), weighted sum into dst, ELU.
//
// R2 changes vs R1 (1427 us):
//   1. starts[N+1] precomputed by an edge-parallel prologue (removes the 40-step
//      dependent binary search every wave paid).
//   2. Main loop runs TWO independent online-softmax streams (even/odd edges),
//      merged at the end: 2 outstanding 1KB loads/wave + 2 independent
//      shuffle/exp chains instead of one serial chain.

constexpr int HD = 256;            // H*D floats per row = 64 float4
constexpr float NEG_SLOPE = 0.01f;

// ---------- prologue: starts[n] = first edge index with dst[e] >= n ----------
__global__ __launch_bounds__(256) void build_starts(
    const int* __restrict__ dst, int* __restrict__ starts, int E, int N)
{
    const int i = blockIdx.x * blockDim.x + threadIdx.x;
    if (i >= E) return;
    const int d = dst[i];
    const int p = (i == 0) ? -1 : dst[i - 1];
    for (int n = p + 1; n <= d; ++n) starts[n] = i;   // gaps are tiny (Poisson)
    if (i == E - 1)
        for (int n = d + 1; n <= N; ++n) starts[n] = E;
}

// ---------- main fused kernel: one wave per dst node ----------
__global__ __launch_bounds__(256) void magnn_fused(
    const float* __restrict__ h_meta,   // [E, 256]
    const float* __restrict__ attn_r,   // [256]
    const int*   __restrict__ starts,   // [N+1]
    float*       __restrict__ out,      // [N, 256]
    int N)
{
    const int node = blockIdx.x * 4 + (threadIdx.x >> 6);
    const int lane = threadIdx.x & 63;
    if (node >= N) return;

    const int s = starts[node];
    const int e = starts[node + 1];

    const float4 ar = reinterpret_cast<const float4*>(attn_r)[lane];
    const float4* __restrict__ hrow = reinterpret_cast<const float4*>(h_meta);

    // two independent online-softmax streams
    float  m0 = -INFINITY, l0 = 0.0f;
    float  m1 = -INFINITY, l1 = 0.0f;
    float4 a0 = make_float4(0.f, 0.f, 0.f, 0.f);
    float4 a1 = make_float4(0.f, 0.f, 0.f, 0.f);

    auto update = [&](float& m, float& l, float4& a, const float4& hv) {
        float part = hv.x * ar.x + hv.y * ar.y + hv.z * ar.z + hv.w * ar.w;
        part += __shfl_xor(part, 1);           // 8-lane head group reduce
        part += __shfl_xor(part, 2);
        part += __shfl_xor(part, 4);
        const float el = part > 0.0f ? part : NEG_SLOPE * part;  // leaky_relu
        const float mn = fmaxf(m, el);
        const float sc = __expf(m - mn);       // first edge: exp(-inf)=0
        const float p  = __expf(el - mn);
        l = l * sc + p;
        a.x = a.x * sc + p * hv.x;
        a.y = a.y * sc + p * hv.y;
        a.z = a.z * sc + p * hv.z;
        a.w = a.w * sc + p * hv.w;
        m = mn;
    };

    int i = s;
    for (; i + 2 <= e; i += 2) {
        // issue both loads before either chain consumes them
        const float4 h0 = hrow[i * 64 + lane];
        const float4 h1 = hrow[(i + 1) * 64 + lane];
        update(m0, l0, a0, h0);
        update(m1, l1, a1, h1);
    }
    if (i < e) {                                // wave-uniform branch
        const float4 h0 = hrow[i * 64 + lane];
        update(m0, l0, a0, h0);
    }

    // merge the two streams
    const float mn = fmaxf(m0, m1);
    const float s0 = (m0 > -INFINITY) ? __expf(m0 - mn) : 0.0f;
    const float s1 = (m1 > -INFINITY) ? __expf(m1 - mn) : 0.0f;
    const float l  = l0 * s0 + l1 * s1;

    float4 o;
    o.x = a0.x * s0 + a1.x * s1;
    o.y = a0.y * s0 + a1.y * s1;
    o.z = a0.z * s0 + a1.z * s1;
    o.w = a0.w * s0 + a1.w * s1;

    const float inv = (l > 0.0f) ? 1.0f / l : 0.0f;   // degree-0 -> elu(0)=0
    o.x *= inv; o.y *= inv; o.z *= inv; o.w *= inv;

    o.x = o.x > 0.0f ? o.x : expm1f(o.x);             // elu, alpha=1
    o.y = o.y > 0.0f ? o.y : expm1f(o.y);
    o.z = o.z > 0.0f ? o.z : expm1f(o.z);
    o.w = o.w > 0.0f ? o.w : expm1f(o.w);

    reinterpret_cast<float4*>(out)[node * 64 + lane] = o;
}

extern "C" void kernel_launch(void* const* d_in, const int* in_sizes, int n_in,
                              void* d_out, int out_size, void* d_ws, size_t ws_size,
                              hipStream_t stream) {
    const float* h_meta = (const float*)d_in[0];
    const float* attn_r = (const float*)d_in[1];
    const int*   dst    = (const int*)d_in[2];
    float*       out    = (float*)d_out;

    const int E = in_sizes[2];          // 1,000,000
    const int N = out_size / HD;        // 100,000

    int* starts = (int*)d_ws;           // N+1 ints, written fully every call

    build_starts<<<(E + 255) / 256, 256, 0, stream>>>(dst, starts, E, N);

    const int grid = (N + 3) / 4;       // 4 waves (nodes) per 256-thread block
    magnn_fused<<<grid, 256, 0, stream>>>(h_meta, attn_r, starts, out, N);
}